// Round 6
// baseline (405.723 us; speedup 1.0000x reference)
//
#include <hip/hip_runtime.h>
#include <stdint.h>

#define DD 512
#define HH 8
#define DOO 64
#define ALPHA 0.2f

typedef __attribute__((ext_vector_type(8))) short short8;
typedef __attribute__((ext_vector_type(4))) float floatx4;
typedef __attribute__((ext_vector_type(4))) unsigned short u16x4;
typedef unsigned short u16;

static __device__ __forceinline__ float bf2f(u16 u){
  union { unsigned int u; float f; } c; c.u = ((unsigned int)u) << 16; return c.f;
}
static __device__ __forceinline__ u16 f2bf(float f){
  union { float f; unsigned int u; } c; c.f = f;
  unsigned int u = c.u;
  unsigned int r = (u + 0x7FFFu + ((u >> 16) & 1u)) >> 16;
  return (u16)r;
}
static __device__ __forceinline__ float leaky(float s){ return (s >= 0.f) ? s : ALPHA * s; }
static __device__ __forceinline__ float elu(float v){ return (v > 0.f) ? v : (__expf(v) - 1.f); }

#define DOT2(accv, pairv, wv) \
  asm("v_dot2_f32_bf16 %0, %1, %2, %0" : "+v"(accv) : "v"(pairv), "v"(wv))

// pack two zero-extended u16 loads (z_e0[c], z_e1[c]) into one bf16x2 dword
#define PACK2(dst, lo, hi) \
  asm("v_lshl_or_b32 %0, %1, 16, %2" : "=v"(dst) : "v"(hi), "v"(lo))

#define GLOAD_LDS16(g, l) \
  __builtin_amdgcn_global_load_lds((const __attribute__((address_space(1))) void*)(g), \
                                   (__attribute__((address_space(3))) void*)(l), 16, 0, 0)

// ---------------- fused prep: x->bf16, W transposes, degree count, zero sentinel row ----------------
__global__ void k_prep(const float* __restrict__ h, u16* __restrict__ xb,
                       const float* __restrict__ W1, u16* __restrict__ wbt1,
                       const float* __restrict__ Wout, u16* __restrict__ wbt2,
                       const int* __restrict__ dst, int* deg, u16* __restrict__ z1b,
                       int n4, int E, int N){
  int i = blockIdx.x * blockDim.x + threadIdx.x;
  if (i < n4){
    float4 v = ((const float4*)h)[i];
    u16x4 o;
    o[0] = f2bf(v.x); o[1] = f2bf(v.y); o[2] = f2bf(v.z); o[3] = f2bf(v.w);
    ((u16x4*)xb)[i] = o;
    return;
  }
  i -= n4;
  if (i < HH * DD * DOO / 8){
    int idx0 = i * 8;
    #pragma unroll
    for (int t = 0; t < 8; t++){
      int idx = idx0 + t;
      int hh = idx >> 15;
      int rem = idx & 32767;
      int k = rem >> 6;
      int dd = rem & 63;
      wbt1[(hh * 64 + dd) * DD + k] = f2bf(W1[idx]);
    }
    return;
  }
  i -= HH * DD * DOO / 8;
  if (i < DD * DD){
    int k = i >> 9, n = i & 511;
    wbt2[n * DD + k] = f2bf(Wout[i]);
    return;
  }
  i -= DD * DD;
  if (i < E){
    atomicAdd(&deg[dst[i]], 1);
    return;
  }
  i -= E;
  if (i < DD / 4){                      // zero sentinel row z[N]
    u16x4 zz; zz[0]=0; zz[1]=0; zz[2]=0; zz[3]=0;
    ((u16x4*)(z1b + (size_t)N * DD))[i] = zz;
  }
}

// ---------------- CSR build: pad each node's list to multiple of 4 ----------------
__global__ void k_ntot(const int* __restrict__ deg, int* __restrict__ ntot, int N){
  int n = blockIdx.x * blockDim.x + threadIdx.x;
  if (n < N) ntot[n] = (deg[n] + 3) & ~3;
}

__global__ void k_scan(const int* __restrict__ ntot, int* __restrict__ off,
                       int* __restrict__ cursor, int N){
  __shared__ int sm[1024];
  int tid = threadIdx.x;
  const int per = 16;
  int base = tid * per;
  int loc[per];
  int t = 0;
  #pragma unroll
  for (int i = 0; i < per; i++){ int v = (base + i < N) ? ntot[base + i] : 0; loc[i] = v; t += v; }
  sm[tid] = t; __syncthreads();
  for (int o = 1; o < 1024; o <<= 1){
    int v = 0;
    if (tid >= o) v = sm[tid - o];
    __syncthreads();
    sm[tid] += v;
    __syncthreads();
  }
  int run = sm[tid] - t;
  #pragma unroll
  for (int i = 0; i < per; i++){
    if (base + i < N){ off[base + i] = run; cursor[base + i] = run; }
    run += loc[i];
  }
  if (tid == 1023) off[N] = run;
}

__global__ void k_scatter(const int* __restrict__ src, const int* __restrict__ dst,
                          const int* __restrict__ off, int* cursor, int* __restrict__ csr,
                          int E, int N){
  int i = blockIdx.x * blockDim.x + threadIdx.x;
  if (i < 512){                             // sentinel-fill the prefetch-overrun slack past off[N]
    csr[off[N] + i] = N;
  }
  if (i < E){
    int d = dst[i];
    int p = atomicAdd(&cursor[d], 1);
    csr[p] = src[i];
  }
}

// fill per-node pad slots (<=3) with sentinel N (gathers the zero row, weight forced 0)
__global__ void k_fillpad(const int* __restrict__ off, const int* __restrict__ cursor,
                          int* __restrict__ csr, int N){
  int n = blockIdx.x * blockDim.x + threadIdx.x;
  if (n >= N) return;
  int e = off[n + 1];
  for (int q = cursor[n]; q < e; q++) csr[q] = N;
}

// ---------------- bf16 MFMA GEMM: BK=64, XOR-swizzled LDS, n-fastest grid ----------------
__global__ __launch_bounds__(256) void k_gemm(const u16* __restrict__ A,
                                              const u16* __restrict__ BT,
                                              u16* __restrict__ C, int M){
  __shared__ __attribute__((aligned(16))) u16 As[128 * 64];
  __shared__ __attribute__((aligned(16))) u16 Bs[128 * 64];
  const int tid = threadIdx.x;
  const int wid = tid >> 6, lane = tid & 63;
  const int n0 = blockIdx.x * 128, m0 = blockIdx.y * 128;
  const int wr = wid >> 1, wc = wid & 1;
  const int row16 = lane & 15, kg = lane >> 4;
  floatx4 acc[4][4];
  #pragma unroll
  for (int i = 0; i < 4; i++)
    #pragma unroll
    for (int j = 0; j < 4; j++) acc[i][j] = (floatx4)0.0f;

  for (int kt = 0; kt < DD; kt += 64){
    #pragma unroll
    for (int i = 0; i < 4; i++){
      int chunk = i * 256 + tid;          // LDS granule 0..1023 (linear dest)
      int m = chunk >> 3, g = chunk & 7;
      int gs = g ^ (m & 7);               // inverse-swizzled global source granule
      GLOAD_LDS16(A + (size_t)(m0 + m) * DD + kt + gs * 8, &As[chunk * 8]);
      GLOAD_LDS16(BT + (size_t)(n0 + m) * DD + kt + gs * 8, &Bs[chunk * 8]);
    }
    __syncthreads();
    short8 af[4][2], bf[4][2];
    #pragma unroll
    for (int mi = 0; mi < 4; mi++)
      #pragma unroll
      for (int kk = 0; kk < 2; kk++){
        int row = wr * 64 + mi * 16 + row16;
        int gr = (kk * 4 + kg) ^ (row & 7);
        af[mi][kk] = *(const short8*)(&As[(row * 8 + gr) * 8]);
      }
    #pragma unroll
    for (int ni = 0; ni < 4; ni++)
      #pragma unroll
      for (int kk = 0; kk < 2; kk++){
        int row = wc * 64 + ni * 16 + row16;
        int gr = (kk * 4 + kg) ^ (row & 7);
        bf[ni][kk] = *(const short8*)(&Bs[(row * 8 + gr) * 8]);
      }
    #pragma unroll
    for (int kk = 0; kk < 2; kk++)
      #pragma unroll
      for (int mi = 0; mi < 4; mi++)
        #pragma unroll
        for (int ni = 0; ni < 4; ni++)
          acc[mi][ni] = __builtin_amdgcn_mfma_f32_16x16x32_bf16(af[mi][kk], bf[ni][kk], acc[mi][ni], 0, 0, 0);
    __syncthreads();
  }
  #pragma unroll
  for (int mi = 0; mi < 4; mi++)
    #pragma unroll
    for (int ni = 0; ni < 4; ni++)
      #pragma unroll
      for (int j = 0; j < 4; j++){
        int r = m0 + wr * 64 + mi * 16 + kg * 4 + j;
        int c = n0 + wc * 64 + ni * 16 + row16;
        C[(size_t)r * DD + c] = f2bf(acc[mi][ni][j]);
      }
}

// ---------------- attention scores ----------------
__global__ void k_scores1(const u16* __restrict__ z, const float* __restrict__ a1,
                          float* __restrict__ es, float* __restrict__ ed, int N){
  int wid = threadIdx.x >> 6, lane = threadIdx.x & 63;
  int n = blockIdx.x * 4 + wid;
  if (n >= N) return;
  int h = lane >> 3, j8 = lane & 7;
  short8 zv = *(const short8*)(z + (size_t)n * DD + lane * 8);
  float esv = 0.f, edv = 0.f;
  #pragma unroll
  for (int t = 0; t < 8; t++){
    float f = bf2f((u16)zv[t]);
    esv += f * a1[h * 128 + j8 * 8 + t];
    edv += f * a1[h * 128 + 64 + j8 * 8 + t];
  }
  #pragma unroll
  for (int d2 = 1; d2 < 8; d2 <<= 1){ esv += __shfl_xor(esv, d2); edv += __shfl_xor(edv, d2); }
  if (j8 == 0){ es[n * 8 + h] = esv; ed[n * 8 + h] = edv; }
}

__global__ void k_scores2(const u16* __restrict__ z, const float* __restrict__ aout,
                          float* __restrict__ es, float* __restrict__ ed, int N){
  int wid = threadIdx.x >> 6, lane = threadIdx.x & 63;
  int n = blockIdx.x * 4 + wid;
  if (n >= N) return;
  short8 zv = *(const short8*)(z + (size_t)n * DD + lane * 8);
  float esv = 0.f, edv = 0.f;
  #pragma unroll
  for (int t = 0; t < 8; t++){
    float f = bf2f((u16)zv[t]);
    esv += f * aout[lane * 8 + t];
    edv += f * aout[512 + lane * 8 + t];
  }
  #pragma unroll
  for (int d2 = 1; d2 < 64; d2 <<= 1){ esv += __shfl_xor(esv, d2); edv += __shfl_xor(edv, d2); }
  if (lane == 0){ es[n] = esv; ed[n] = edv; }
}

// ---------------- edge weights (softmax numerators), hoisted out of aggregation ----------------
// One wave per node; sentinel src==N gets weight 0. Pairs packed bf16x2, [head][pair] layout
// (shard==head in k_agg1 streams its head's weights contiguously).
__global__ void k_edgew1(const float* __restrict__ es, const float* __restrict__ ed,
                         const int* __restrict__ off,
                         const int* __restrict__ csr, unsigned* __restrict__ wp,
                         float* __restrict__ den1, int N, int ep2){
  int wid = threadIdx.x >> 6, lane = threadIdx.x & 63;
  int n = blockIdx.x * 4 + wid;
  if (n >= N) return;
  int o0 = off[n], cntp = off[n + 1] - o0;
  float edh[8];
  {
    float4 d0 = *(const float4*)(ed + (size_t)n * 8);
    float4 d1 = *(const float4*)(ed + (size_t)n * 8 + 4);
    edh[0]=d0.x; edh[1]=d0.y; edh[2]=d0.z; edh[3]=d0.w;
    edh[4]=d1.x; edh[5]=d1.y; edh[6]=d1.z; edh[7]=d1.w;
  }
  float den[8];
  #pragma unroll
  for (int h = 0; h < 8; h++) den[h] = 0.f;
  for (int base = 0; base < cntp; base += 64){
    int e = base + lane;
    int s = csr[o0 + e];                   // overrun lands in next node / sentinel slack
    bool valid = (e < cntp) && (s != N);
    float4 e0 = *(const float4*)(es + (size_t)s * 8);       // s==N reads slack floats
    float4 e1 = *(const float4*)(es + (size_t)s * 8 + 4);
    float ev[8] = {e0.x, e0.y, e0.z, e0.w, e1.x, e1.y, e1.z, e1.w};
    float wv[8];
    #pragma unroll
    for (int h = 0; h < 8; h++){
      float w = __expf(leaky(ev[h] + edh[h]));
      wv[h] = valid ? w : 0.f;
      den[h] += wv[h];
    }
    #pragma unroll
    for (int h = 0; h < 8; h++){
      float wn = __shfl_down(wv[h], 1);
      if (!(lane & 1) && e < cntp){
        unsigned pk;
        asm("v_cvt_pk_bf16_f32 %0, %1, %2" : "=v"(pk) : "v"(wv[h]), "v"(wn));
        wp[(size_t)h * ep2 + ((o0 + e) >> 1)] = pk;
      }
    }
  }
  #pragma unroll
  for (int h = 0; h < 8; h++){
    float d = den[h];
    #pragma unroll
    for (int d2 = 1; d2 < 64; d2 <<= 1) d += __shfl_xor(d, d2);
    if (lane == 0) den1[(size_t)n * 8 + h] = d;
  }
}

__global__ void k_edgew2(const float* __restrict__ es, const float* __restrict__ ed,
                         const int* __restrict__ off,
                         const int* __restrict__ csr, unsigned* __restrict__ wp,
                         float* __restrict__ den2, int N){
  int wid = threadIdx.x >> 6, lane = threadIdx.x & 63;
  int n = blockIdx.x * 4 + wid;
  if (n >= N) return;
  int o0 = off[n], cntp = off[n + 1] - o0;
  float edn = ed[n];
  float dsum = 0.f;
  for (int base = 0; base < cntp; base += 64){
    int e = base + lane;
    int s = csr[o0 + e];
    bool valid = (e < cntp) && (s != N);
    float w = __expf(leaky(es[s] + edn));
    w = valid ? w : 0.f;
    dsum += w;
    float wn = __shfl_down(w, 1);
    if (!(lane & 1) && e < cntp){
      unsigned pk;
      asm("v_cvt_pk_bf16_f32 %0, %1, %2" : "=v"(pk) : "v"(w), "v"(wn));
      wp[(o0 + e) >> 1] = pk;
    }
  }
  #pragma unroll
  for (int d2 = 1; d2 < 64; d2 <<= 1) dsum += __shfl_xor(dsum, d2);
  if (lane == 0) den2[n] = dsum;
}

// ---------------- XCD-sharded aggregation ----------------
// Wave = (node, col-shard). shard = blockIdx.x & 7 -> pinned to one XCD by the round-robin
// block->XCD dispatch, so each XCD gathers only its 2MB column-slice of z (L2-resident).
// Lane owns 1 col (u16); per edge-pair: 2 ushort gathers + pack + dot2. Shard == head in agg1.
__global__ __launch_bounds__(256) void k_agg1(const u16* __restrict__ z,
    const unsigned* __restrict__ wp, const float* __restrict__ den1,
    const int* __restrict__ off, const int* __restrict__ csr,
    u16* __restrict__ hcat, int N, int ep2){
  int tid = threadIdx.x;
  int wid = tid >> 6, lane = tid & 63;
  int s = blockIdx.x & 7;                     // shard == head
  int n = (blockIdx.x >> 3) * 4 + wid;
  if (n >= N) return;
  int o0 = off[n];
  int itn = (off[n + 1] - o0) >> 2;           // 2 pairs (4 edges) per iteration, exact
  const int4* cp4 = (const int4*)(csr + o0);
  const uint2* wpb = (const uint2*)(wp + (size_t)s * ep2 + (o0 >> 1));
  const u16* zs = z + s * 64 + lane;          // + src*DD per row
  float acc = 0.f;

  unsigned dA0, dA1, dB0, dB1, eA0, eA1, eB0, eB1;
  uint2 aq0, aq1;
  int4 c1;
  {
    int4 c0 = cp4[0];
    c1 = cp4[1];
    aq0 = wpb[0]; aq1 = wpb[1];
    dA0 = zs[(size_t)(unsigned)c0.x * DD]; dA1 = zs[(size_t)(unsigned)c0.y * DD];
    dB0 = zs[(size_t)(unsigned)c0.z * DD]; dB1 = zs[(size_t)(unsigned)c0.w * DD];
    eA0 = zs[(size_t)(unsigned)c1.x * DD]; eA1 = zs[(size_t)(unsigned)c1.y * DD];
    eB0 = zs[(size_t)(unsigned)c1.z * DD]; eB1 = zs[(size_t)(unsigned)c1.w * DD];
  }
  for (int it = 0; it < itn; ++it){
    int4 cn = cp4[it + 2];                    // overrun lands in next node / sentinel slack
    uint2 an = wpb[it + 2];
    unsigned nA0 = zs[(size_t)(unsigned)cn.x * DD], nA1 = zs[(size_t)(unsigned)cn.y * DD];
    unsigned nB0 = zs[(size_t)(unsigned)cn.z * DD], nB1 = zs[(size_t)(unsigned)cn.w * DD];
    unsigned pA, pB;
    PACK2(pA, dA0, dA1);
    PACK2(pB, dB0, dB1);
    DOT2(acc, pA, aq0.x);
    DOT2(acc, pB, aq0.y);
    dA0 = eA0; dA1 = eA1; dB0 = eB0; dB1 = eB1; aq0 = aq1;
    eA0 = nA0; eA1 = nA1; eB0 = nB0; eB1 = nB1; aq1 = an;
  }
  float inv = 1.f / den1[(size_t)n * 8 + s];
  hcat[(size_t)n * DD + s * 64 + lane] = f2bf(elu(acc * inv));
}

__global__ __launch_bounds__(256) void k_agg2(const u16* __restrict__ z,
    const unsigned* __restrict__ wp, const float* __restrict__ den2,
    const int* __restrict__ off, const int* __restrict__ csr,
    const u16* __restrict__ xb, float* __restrict__ out, int N){
  int tid = threadIdx.x;
  int wid = tid >> 6, lane = tid & 63;
  int s = blockIdx.x & 7;
  int n = (blockIdx.x >> 3) * 4 + wid;
  if (n >= N) return;
  int o0 = off[n];
  int itn = (off[n + 1] - o0) >> 2;
  const int4* cp4 = (const int4*)(csr + o0);
  const uint2* wpb = (const uint2*)(wp + (o0 >> 1));
  const u16* zs = z + s * 64 + lane;
  float acc = 0.f;

  unsigned dA0, dA1, dB0, dB1, eA0, eA1, eB0, eB1;
  uint2 aq0, aq1;
  int4 c1;
  {
    int4 c0 = cp4[0];
    c1 = cp4[1];
    aq0 = wpb[0]; aq1 = wpb[1];
    dA0 = zs[(size_t)(unsigned)c0.x * DD]; dA1 = zs[(size_t)(unsigned)c0.y * DD];
    dB0 = zs[(size_t)(unsigned)c0.z * DD]; dB1 = zs[(size_t)(unsigned)c0.w * DD];
    eA0 = zs[(size_t)(unsigned)c1.x * DD]; eA1 = zs[(size_t)(unsigned)c1.y * DD];
    eB0 = zs[(size_t)(unsigned)c1.z * DD]; eB1 = zs[(size_t)(unsigned)c1.w * DD];
  }
  for (int it = 0; it < itn; ++it){
    int4 cn = cp4[it + 2];
    uint2 an = wpb[it + 2];
    unsigned nA0 = zs[(size_t)(unsigned)cn.x * DD], nA1 = zs[(size_t)(unsigned)cn.y * DD];
    unsigned nB0 = zs[(size_t)(unsigned)cn.z * DD], nB1 = zs[(size_t)(unsigned)cn.w * DD];
    unsigned pA, pB;
    PACK2(pA, dA0, dA1);
    PACK2(pB, dB0, dB1);
    DOT2(acc, pA, aq0.x);
    DOT2(acc, pB, aq0.y);
    dA0 = eA0; dA1 = eA1; dB0 = eB0; dB1 = eB1; aq0 = aq1;
    eA0 = nA0; eA1 = nA1; eB0 = nB0; eB1 = nB1; aq1 = an;
  }
  float inv = 1.f / den2[n];
  int c = s * 64 + lane;
  float xv = bf2f(xb[(size_t)n * DD + c]);
  out[(size_t)n * DD + c] = elu(acc * inv) + xv;
}

// ---------------- launcher ----------------
extern "C" void kernel_launch(void* const* d_in, const int* in_sizes, int n_in,
                              void* d_out, int out_size, void* d_ws, size_t ws_size,
                              hipStream_t stream){
  const float* h   = (const float*)d_in[0];
  const float* W1  = (const float*)d_in[1];
  const float* a1  = (const float*)d_in[2];
  const float* Wout= (const float*)d_in[3];
  const float* aout= (const float*)d_in[4];
  const int* src   = (const int*)d_in[5];
  const int* dst   = (const int*)d_in[6];
  float* out = (float*)d_out;
  const int N = in_sizes[0] / DD;     // 16384
  const int E = in_sizes[5];          // 540672
  const int EP = E + 3 * N + 512;     // padded-CSR capacity (<=3 pads/node + prefetch slack)
  const int ep2 = EP >> 1;            // pair capacity

  char* p = (char*)d_ws;
  auto alloc = [&](size_t bytes) -> char* {
    char* r = p;
    p += (bytes + 255) & ~(size_t)255;
    return r;
  };
  u16* xb    = (u16*)alloc((size_t)N * DD * 2);
  u16* z1b   = (u16*)alloc((size_t)(N + 1) * DD * 2);   // +1: zero sentinel row; reused as z2b
  u16* hcat  = (u16*)alloc((size_t)N * DD * 2);
  u16* wbt1  = (u16*)alloc((size_t)DD * DD * 2);
  u16* wbt2  = (u16*)alloc((size_t)DD * DD * 2);
  float* es1 = (float*)alloc(((size_t)N * HH + 8) * 4); // +8: sentinel-read slack
  float* ed1 = (float*)alloc((size_t)N * HH * 4);
  float* es2 = (float*)alloc(((size_t)N + 8) * 4);
  float* ed2 = (float*)alloc((size_t)N * 4);
  float* den1= (float*)alloc((size_t)N * HH * 4);
  float* den2= (float*)alloc((size_t)N * 4);
  int* deg   = (int*)alloc((size_t)N * 4);
  int* ntot  = (int*)alloc((size_t)N * 4);
  int* off   = (int*)alloc((size_t)(N + 1) * 4);
  int* cursor= (int*)alloc((size_t)N * 4);
  int* csr   = (int*)alloc((size_t)EP * 4);
  unsigned* wp1 = (unsigned*)alloc(((size_t)HH * ep2 + 64) * 4);  // [head][pair]
  unsigned* wp2 = (unsigned*)alloc(((size_t)ep2 + 64) * 4);

  // only deg needs zeroing (everything else fully written before read)
  hipMemsetAsync(deg, 0, (size_t)N * 4, stream);

  int n4 = N * DD / 4;
  int prep_threads = n4 + HH * DD * DOO / 8 + DD * DD + E + DD / 4;
  k_prep<<<(prep_threads + 255) / 256, 256, 0, stream>>>(h, xb, W1, wbt1, Wout, wbt2,
                                                         dst, deg, z1b, n4, E, N);
  k_ntot<<<(N + 255) / 256, 256, 0, stream>>>(deg, ntot, N);
  k_scan<<<1, 1024, 0, stream>>>(ntot, off, cursor, N);
  k_scatter<<<(E + 255) / 256, 256, 0, stream>>>(src, dst, off, cursor, csr, E, N);
  k_fillpad<<<(N + 255) / 256, 256, 0, stream>>>(off, cursor, csr, N);

  dim3 gg(DD / 128, N / 128);     // x = n-tile (4), y = m-tile (128): A-panel reuse
  dim3 ga(8 * ((N + 3) / 4));     // (node-group, shard): shard = blockIdx.x & 7 -> XCD-pinned
  dim3 gw((N + 3) / 4);

  k_gemm<<<gg, 256, 0, stream>>>(xb, wbt1, z1b, N);
  k_scores1<<<(N + 3) / 4, 256, 0, stream>>>(z1b, a1, es1, ed1, N);
  k_edgew1<<<gw, 256, 0, stream>>>(es1, ed1, off, csr, wp1, den1, N, ep2);
  k_agg1<<<ga, 256, 0, stream>>>(z1b, wp1, den1, off, csr, hcat, N, ep2);

  k_gemm<<<gg, 256, 0, stream>>>(hcat, wbt2, z1b, N);
  k_scores2<<<(N + 3) / 4, 256, 0, stream>>>(z1b, aout, es2, ed2, N);
  k_edgew2<<<gw, 256, 0, stream>>>(es2, ed2, off, csr, wp2, den2, N);
  k_agg2<<<ga, 256, 0, stream>>>(z1b, wp2, den2, off, csr, xb, out, N);
}

// Round 8
// 281.753 us; speedup vs baseline: 1.4400x; 1.4400x over previous
//
#include <hip/hip_runtime.h>
#include <stdint.h>

#define DD 512
#define HH 8
#define DOO 64
#define ALPHA 0.2f

typedef __attribute__((ext_vector_type(8))) short short8;
typedef __attribute__((ext_vector_type(4))) float floatx4;
typedef __attribute__((ext_vector_type(4))) unsigned short u16x4;
typedef unsigned short u16;

static __device__ __forceinline__ float bf2f(u16 u){
  union { unsigned int u; float f; } c; c.u = ((unsigned int)u) << 16; return c.f;
}
static __device__ __forceinline__ u16 f2bf(float f){
  union { float f; unsigned int u; } c; c.f = f;
  unsigned int u = c.u;
  unsigned int r = (u + 0x7FFFu + ((u >> 16) & 1u)) >> 16;
  return (u16)r;
}
static __device__ __forceinline__ float leaky(float s){ return (s >= 0.f) ? s : ALPHA * s; }
static __device__ __forceinline__ float elu(float v){ return (v > 0.f) ? v : (__expf(v) - 1.f); }

// pair (z0[c], z1[c]) bf16x2 from two edges' dwords (each dword = cols c,c+1 of one row)
// v_perm pool: sel 0-3 -> src1 bytes, 4-7 -> src0 bytes
#define PERM_LO 0x01000504u
#define PERM_HI 0x03020706u

#define DOT2(accv, pairv, wv) \
  asm("v_dot2_f32_bf16 %0, %1, %2, %0" : "+v"(accv) : "v"(pairv), "v"(wv))

#define GLOAD_LDS16(g, l) \
  __builtin_amdgcn_global_load_lds((const __attribute__((address_space(1))) void*)(g), \
                                   (__attribute__((address_space(3))) void*)(l), 16, 0, 0)

// ---------------- fused prep: x->bf16, W transposes, degree count, zero sentinel row ----------------
__global__ void k_prep(const float* __restrict__ h, u16* __restrict__ xb,
                       const float* __restrict__ W1, u16* __restrict__ wbt1,
                       const float* __restrict__ Wout, u16* __restrict__ wbt2,
                       const int* __restrict__ dst, int* deg, u16* __restrict__ z1b,
                       int n4, int E, int N){
  int i = blockIdx.x * blockDim.x + threadIdx.x;
  if (i < n4){
    float4 v = ((const float4*)h)[i];
    u16x4 o;
    o[0] = f2bf(v.x); o[1] = f2bf(v.y); o[2] = f2bf(v.z); o[3] = f2bf(v.w);
    ((u16x4*)xb)[i] = o;
    return;
  }
  i -= n4;
  if (i < HH * DD * DOO / 8){
    int idx0 = i * 8;
    #pragma unroll
    for (int t = 0; t < 8; t++){
      int idx = idx0 + t;
      int hh = idx >> 15;
      int rem = idx & 32767;
      int k = rem >> 6;
      int dd = rem & 63;
      wbt1[(hh * 64 + dd) * DD + k] = f2bf(W1[idx]);
    }
    return;
  }
  i -= HH * DD * DOO / 8;
  if (i < DD * DD){
    int k = i >> 9, n = i & 511;
    wbt2[n * DD + k] = f2bf(Wout[i]);
    return;
  }
  i -= DD * DD;
  if (i < E){
    atomicAdd(&deg[dst[i]], 1);
    return;
  }
  i -= E;
  if (i < DD / 4){                      // zero sentinel row z[N]
    u16x4 zz; zz[0]=0; zz[1]=0; zz[2]=0; zz[3]=0;
    ((u16x4*)(z1b + (size_t)N * DD))[i] = zz;
  }
}

// ---------------- CSR build: pad each node's list to multiple of 4 ----------------
__global__ void k_ntot(const int* __restrict__ deg, int* __restrict__ ntot, int N){
  int n = blockIdx.x * blockDim.x + threadIdx.x;
  if (n < N) ntot[n] = (deg[n] + 3) & ~3;
}

__global__ void k_scan(const int* __restrict__ ntot, int* __restrict__ off,
                       int* __restrict__ cursor, int N){
  __shared__ int sm[1024];
  int tid = threadIdx.x;
  const int per = 16;
  int base = tid * per;
  int loc[per];
  int t = 0;
  #pragma unroll
  for (int i = 0; i < per; i++){ int v = (base + i < N) ? ntot[base + i] : 0; loc[i] = v; t += v; }
  sm[tid] = t; __syncthreads();
  for (int o = 1; o < 1024; o <<= 1){
    int v = 0;
    if (tid >= o) v = sm[tid - o];
    __syncthreads();
    sm[tid] += v;
    __syncthreads();
  }
  int run = sm[tid] - t;
  #pragma unroll
  for (int i = 0; i < per; i++){
    if (base + i < N){ off[base + i] = run; cursor[base + i] = run; }
    run += loc[i];
  }
  if (tid == 1023) off[N] = run;
}

__global__ void k_scatter(const int* __restrict__ src, const int* __restrict__ dst,
                          const int* __restrict__ off, int* cursor, int* __restrict__ csr,
                          int E, int N){
  int i = blockIdx.x * blockDim.x + threadIdx.x;
  if (i < 512){                             // sentinel-fill the prefetch-overrun slack past off[N]
    csr[off[N] + i] = N;
  }
  if (i < E){
    int d = dst[i];
    int p = atomicAdd(&cursor[d], 1);
    csr[p] = src[i];
  }
}

// fill per-node pad slots (<=3) with sentinel N (gathers the zero row, weight forced 0)
__global__ void k_fillpad(const int* __restrict__ off, const int* __restrict__ cursor,
                          int* __restrict__ csr, int N){
  int n = blockIdx.x * blockDim.x + threadIdx.x;
  if (n >= N) return;
  int e = off[n + 1];
  for (int q = cursor[n]; q < e; q++) csr[q] = N;
}

// ---------------- bf16 MFMA GEMM: BK=64, XOR-swizzled LDS, n-fastest grid ----------------
__global__ __launch_bounds__(256) void k_gemm(const u16* __restrict__ A,
                                              const u16* __restrict__ BT,
                                              u16* __restrict__ C, int M){
  __shared__ __attribute__((aligned(16))) u16 As[128 * 64];
  __shared__ __attribute__((aligned(16))) u16 Bs[128 * 64];
  const int tid = threadIdx.x;
  const int wid = tid >> 6, lane = tid & 63;
  const int n0 = blockIdx.x * 128, m0 = blockIdx.y * 128;
  const int wr = wid >> 1, wc = wid & 1;
  const int row16 = lane & 15, kg = lane >> 4;
  floatx4 acc[4][4];
  #pragma unroll
  for (int i = 0; i < 4; i++)
    #pragma unroll
    for (int j = 0; j < 4; j++) acc[i][j] = (floatx4)0.0f;

  for (int kt = 0; kt < DD; kt += 64){
    #pragma unroll
    for (int i = 0; i < 4; i++){
      int chunk = i * 256 + tid;          // LDS granule 0..1023 (linear dest)
      int m = chunk >> 3, g = chunk & 7;
      int gs = g ^ (m & 7);               // inverse-swizzled global source granule
      GLOAD_LDS16(A + (size_t)(m0 + m) * DD + kt + gs * 8, &As[chunk * 8]);
      GLOAD_LDS16(BT + (size_t)(n0 + m) * DD + kt + gs * 8, &Bs[chunk * 8]);
    }
    __syncthreads();
    short8 af[4][2], bf[4][2];
    #pragma unroll
    for (int mi = 0; mi < 4; mi++)
      #pragma unroll
      for (int kk = 0; kk < 2; kk++){
        int row = wr * 64 + mi * 16 + row16;
        int gr = (kk * 4 + kg) ^ (row & 7);
        af[mi][kk] = *(const short8*)(&As[(row * 8 + gr) * 8]);
      }
    #pragma unroll
    for (int ni = 0; ni < 4; ni++)
      #pragma unroll
      for (int kk = 0; kk < 2; kk++){
        int row = wc * 64 + ni * 16 + row16;
        int gr = (kk * 4 + kg) ^ (row & 7);
        bf[ni][kk] = *(const short8*)(&Bs[(row * 8 + gr) * 8]);
      }
    #pragma unroll
    for (int kk = 0; kk < 2; kk++)
      #pragma unroll
      for (int mi = 0; mi < 4; mi++)
        #pragma unroll
        for (int ni = 0; ni < 4; ni++)
          acc[mi][ni] = __builtin_amdgcn_mfma_f32_16x16x32_bf16(af[mi][kk], bf[ni][kk], acc[mi][ni], 0, 0, 0);
    __syncthreads();
  }
  #pragma unroll
  for (int mi = 0; mi < 4; mi++)
    #pragma unroll
    for (int ni = 0; ni < 4; ni++)
      #pragma unroll
      for (int j = 0; j < 4; j++){
        int r = m0 + wr * 64 + mi * 16 + kg * 4 + j;
        int c = n0 + wc * 64 + ni * 16 + row16;
        C[(size_t)r * DD + c] = f2bf(acc[mi][ni][j]);
      }
}

// ---------------- attention scores ----------------
__global__ void k_scores1(const u16* __restrict__ z, const float* __restrict__ a1,
                          float* __restrict__ es, float* __restrict__ ed, int N){
  int wid = threadIdx.x >> 6, lane = threadIdx.x & 63;
  int n = blockIdx.x * 4 + wid;
  if (n >= N) return;
  int h = lane >> 3, j8 = lane & 7;
  short8 zv = *(const short8*)(z + (size_t)n * DD + lane * 8);
  float esv = 0.f, edv = 0.f;
  #pragma unroll
  for (int t = 0; t < 8; t++){
    float f = bf2f((u16)zv[t]);
    esv += f * a1[h * 128 + j8 * 8 + t];
    edv += f * a1[h * 128 + 64 + j8 * 8 + t];
  }
  #pragma unroll
  for (int d2 = 1; d2 < 8; d2 <<= 1){ esv += __shfl_xor(esv, d2); edv += __shfl_xor(edv, d2); }
  if (j8 == 0){ es[n * 8 + h] = esv; ed[n * 8 + h] = edv; }
}

__global__ void k_scores2(const u16* __restrict__ z, const float* __restrict__ aout,
                          float* __restrict__ es, float* __restrict__ ed, int N){
  int wid = threadIdx.x >> 6, lane = threadIdx.x & 63;
  int n = blockIdx.x * 4 + wid;
  if (n >= N) return;
  short8 zv = *(const short8*)(z + (size_t)n * DD + lane * 8);
  float esv = 0.f, edv = 0.f;
  #pragma unroll
  for (int t = 0; t < 8; t++){
    float f = bf2f((u16)zv[t]);
    esv += f * aout[lane * 8 + t];
    edv += f * aout[512 + lane * 8 + t];
  }
  #pragma unroll
  for (int d2 = 1; d2 < 64; d2 <<= 1){ esv += __shfl_xor(esv, d2); edv += __shfl_xor(edv, d2); }
  if (lane == 0){ es[n] = esv; ed[n] = edv; }
}

// ---------------- edge weights (softmax numerators), hoisted out of aggregation ----------------
// One wave per node; sentinel src==N gets weight 0. Pairs packed bf16x2, [head][pair] layout.
__global__ void k_edgew1(const float* __restrict__ es, const float* __restrict__ ed,
                         const int* __restrict__ off,
                         const int* __restrict__ csr, unsigned* __restrict__ wp,
                         float* __restrict__ den1, int N, int ep2){
  int wid = threadIdx.x >> 6, lane = threadIdx.x & 63;
  int n = blockIdx.x * 4 + wid;
  if (n >= N) return;
  int o0 = off[n], cntp = off[n + 1] - o0;
  float edh[8];
  {
    float4 d0 = *(const float4*)(ed + (size_t)n * 8);
    float4 d1 = *(const float4*)(ed + (size_t)n * 8 + 4);
    edh[0]=d0.x; edh[1]=d0.y; edh[2]=d0.z; edh[3]=d0.w;
    edh[4]=d1.x; edh[5]=d1.y; edh[6]=d1.z; edh[7]=d1.w;
  }
  float den[8];
  #pragma unroll
  for (int h = 0; h < 8; h++) den[h] = 0.f;
  for (int base = 0; base < cntp; base += 64){
    int e = base + lane;
    int s = csr[o0 + e];                   // overrun lands in next node / sentinel slack
    bool valid = (e < cntp) && (s != N);
    float4 e0 = *(const float4*)(es + (size_t)s * 8);       // s==N reads slack floats
    float4 e1 = *(const float4*)(es + (size_t)s * 8 + 4);
    float ev[8] = {e0.x, e0.y, e0.z, e0.w, e1.x, e1.y, e1.z, e1.w};
    float wv[8];
    #pragma unroll
    for (int h = 0; h < 8; h++){
      float w = __expf(leaky(ev[h] + edh[h]));
      wv[h] = valid ? w : 0.f;
      den[h] += wv[h];
    }
    #pragma unroll
    for (int h = 0; h < 8; h++){
      float wn = __shfl_down(wv[h], 1);
      if (!(lane & 1) && e < cntp){
        unsigned pk;
        asm("v_cvt_pk_bf16_f32 %0, %1, %2" : "=v"(pk) : "v"(wv[h]), "v"(wn));
        wp[(size_t)h * ep2 + ((o0 + e) >> 1)] = pk;
      }
    }
  }
  #pragma unroll
  for (int h = 0; h < 8; h++){
    float d = den[h];
    #pragma unroll
    for (int d2 = 1; d2 < 64; d2 <<= 1) d += __shfl_xor(d, d2);
    if (lane == 0) den1[(size_t)n * 8 + h] = d;
  }
}

__global__ void k_edgew2(const float* __restrict__ es, const float* __restrict__ ed,
                         const int* __restrict__ off,
                         const int* __restrict__ csr, unsigned* __restrict__ wp,
                         float* __restrict__ den2, int N){
  int wid = threadIdx.x >> 6, lane = threadIdx.x & 63;
  int n = blockIdx.x * 4 + wid;
  if (n >= N) return;
  int o0 = off[n], cntp = off[n + 1] - o0;
  float edn = ed[n];
  float dsum = 0.f;
  for (int base = 0; base < cntp; base += 64){
    int e = base + lane;
    int s = csr[o0 + e];
    bool valid = (e < cntp) && (s != N);
    float w = __expf(leaky(es[s] + edn));
    w = valid ? w : 0.f;
    dsum += w;
    float wn = __shfl_down(w, 1);
    if (!(lane & 1) && e < cntp){
      unsigned pk;
      asm("v_cvt_pk_bf16_f32 %0, %1, %2" : "=v"(pk) : "v"(w), "v"(wn));
      wp[(o0 + e) >> 1] = pk;
    }
  }
  #pragma unroll
  for (int d2 = 1; d2 < 64; d2 <<= 1) dsum += __shfl_xor(dsum, d2);
  if (lane == 0) den2[n] = dsum;
}

// ---------------- XCD-pinned slab aggregation ----------------
// Wave = one node, slab = blockIdx.x & 3 covers cols [slab*128, +128) -> slab s pinned to
// XCDs {s, s+4} by round-robin dispatch; each XCD gathers only its 4MB z-slice (L2-resident).
// Lane owns 2 cols (1 dword): wave-uniform rows via s_load csr -> SALU base, zero per-iter
// VALU addressing. 2 pairs/iter, 3-deep pipeline (12 rows in flight) covers L2 latency.
__global__ __launch_bounds__(256) void k_agg1(const u16* __restrict__ z,
    const unsigned* __restrict__ wp, const float* __restrict__ den1,
    const int* __restrict__ off, const int* __restrict__ csr,
    u16* __restrict__ hcat, int N, int ep2){
  int wid = __builtin_amdgcn_readfirstlane(threadIdx.x >> 6);
  int lane = threadIdx.x & 63;
  int slab = blockIdx.x & 3;
  int n = (blockIdx.x >> 2) * 4 + wid;
  if (n >= N) return;
  int o0 = off[n];
  int itn = (off[n + 1] - o0) >> 2;        // 2 pairs (4 edges) per iteration, exact
  const int4* cp4 = (const int4*)(csr + o0);
  const unsigned* zd = (const unsigned*)z + (size_t)slab * 64 + lane;   // + s*256 per row
  int head = 2 * slab + (lane >> 5);       // lanes 0-31 -> head 2s; 32-63 -> 2s+1
  const unsigned* wpb = wp + (size_t)head * ep2 + (o0 >> 1);
  float acc0 = 0.f, acc1 = 0.f;

  int4 cA = cp4[0], cB = cp4[1], cC = cp4[2];
  unsigned aA0 = __builtin_nontemporal_load(wpb + 0), aA1 = __builtin_nontemporal_load(wpb + 1);
  unsigned aB0 = __builtin_nontemporal_load(wpb + 2), aB1 = __builtin_nontemporal_load(wpb + 3);
  unsigned aC0 = __builtin_nontemporal_load(wpb + 4), aC1 = __builtin_nontemporal_load(wpb + 5);
  unsigned rA0 = zd[(size_t)(unsigned)cA.x * 256], rA1 = zd[(size_t)(unsigned)cA.y * 256];
  unsigned rA2 = zd[(size_t)(unsigned)cA.z * 256], rA3 = zd[(size_t)(unsigned)cA.w * 256];
  unsigned rB0 = zd[(size_t)(unsigned)cB.x * 256], rB1 = zd[(size_t)(unsigned)cB.y * 256];
  unsigned rB2 = zd[(size_t)(unsigned)cB.z * 256], rB3 = zd[(size_t)(unsigned)cB.w * 256];
  unsigned rC0 = zd[(size_t)(unsigned)cC.x * 256], rC1 = zd[(size_t)(unsigned)cC.y * 256];
  unsigned rC2 = zd[(size_t)(unsigned)cC.z * 256], rC3 = zd[(size_t)(unsigned)cC.w * 256];

  #pragma unroll 3
  for (int it = 0; it < itn; ++it){
    int4 cN = cp4[it + 3];                 // overrun lands in sentinel slack
    unsigned aN0 = __builtin_nontemporal_load(wpb + 2 * it + 6);
    unsigned aN1 = __builtin_nontemporal_load(wpb + 2 * it + 7);
    unsigned n0 = zd[(size_t)(unsigned)cN.x * 256], n1 = zd[(size_t)(unsigned)cN.y * 256];
    unsigned n2 = zd[(size_t)(unsigned)cN.z * 256], n3 = zd[(size_t)(unsigned)cN.w * 256];
    unsigned pr;
    pr = __builtin_amdgcn_perm(rA0, rA1, PERM_LO); DOT2(acc0, pr, aA0);
    pr = __builtin_amdgcn_perm(rA0, rA1, PERM_HI); DOT2(acc1, pr, aA0);
    pr = __builtin_amdgcn_perm(rA2, rA3, PERM_LO); DOT2(acc0, pr, aA1);
    pr = __builtin_amdgcn_perm(rA2, rA3, PERM_HI); DOT2(acc1, pr, aA1);
    rA0 = rB0; rA1 = rB1; rA2 = rB2; rA3 = rB3; aA0 = aB0; aA1 = aB1;
    rB0 = rC0; rB1 = rC1; rB2 = rC2; rB3 = rC3; aB0 = aC0; aB1 = aC1;
    rC0 = n0;  rC1 = n1;  rC2 = n2;  rC3 = n3;  aC0 = aN0; aC1 = aN1;
  }
  float inv = 1.f / den1[(size_t)n * 8 + head];
  unsigned od = (unsigned)f2bf(elu(acc0 * inv)) | ((unsigned)f2bf(elu(acc1 * inv)) << 16);
  ((unsigned*)(hcat + (size_t)n * DD))[slab * 64 + lane] = od;
}

__global__ __launch_bounds__(256) void k_agg2(const u16* __restrict__ z,
    const unsigned* __restrict__ wp, const float* __restrict__ den2,
    const int* __restrict__ off, const int* __restrict__ csr,
    const u16* __restrict__ xb, float* __restrict__ out, int N){
  int wid = __builtin_amdgcn_readfirstlane(threadIdx.x >> 6);
  int lane = threadIdx.x & 63;
  int slab = blockIdx.x & 3;
  int n = (blockIdx.x >> 2) * 4 + wid;
  if (n >= N) return;
  int o0 = off[n];
  int itn = (off[n + 1] - o0) >> 2;
  const int4* cp4 = (const int4*)(csr + o0);
  const unsigned* zd = (const unsigned*)z + (size_t)slab * 64 + lane;
  const unsigned* wpb = wp + (o0 >> 1);    // single head: wave-uniform weights
  float acc0 = 0.f, acc1 = 0.f;

  int4 cA = cp4[0], cB = cp4[1], cC = cp4[2];
  unsigned aA0 = wpb[0], aA1 = wpb[1];
  unsigned aB0 = wpb[2], aB1 = wpb[3];
  unsigned aC0 = wpb[4], aC1 = wpb[5];
  unsigned rA0 = zd[(size_t)(unsigned)cA.x * 256], rA1 = zd[(size_t)(unsigned)cA.y * 256];
  unsigned rA2 = zd[(size_t)(unsigned)cA.z * 256], rA3 = zd[(size_t)(unsigned)cA.w * 256];
  unsigned rB0 = zd[(size_t)(unsigned)cB.x * 256], rB1 = zd[(size_t)(unsigned)cB.y * 256];
  unsigned rB2 = zd[(size_t)(unsigned)cB.z * 256], rB3 = zd[(size_t)(unsigned)cB.w * 256];
  unsigned rC0 = zd[(size_t)(unsigned)cC.x * 256], rC1 = zd[(size_t)(unsigned)cC.y * 256];
  unsigned rC2 = zd[(size_t)(unsigned)cC.z * 256], rC3 = zd[(size_t)(unsigned)cC.w * 256];

  #pragma unroll 3
  for (int it = 0; it < itn; ++it){
    int4 cN = cp4[it + 3];
    unsigned aN0 = wpb[2 * it + 6], aN1 = wpb[2 * it + 7];
    unsigned n0 = zd[(size_t)(unsigned)cN.x * 256], n1 = zd[(size_t)(unsigned)cN.y * 256];
    unsigned n2 = zd[(size_t)(unsigned)cN.z * 256], n3 = zd[(size_t)(unsigned)cN.w * 256];
    unsigned pr;
    pr = __builtin_amdgcn_perm(rA0, rA1, PERM_LO); DOT2(acc0, pr, aA0);
    pr = __builtin_amdgcn_perm(rA0, rA1, PERM_HI); DOT2(acc1, pr, aA0);
    pr = __builtin_amdgcn_perm(rA2, rA3, PERM_LO); DOT2(acc0, pr, aA1);
    pr = __builtin_amdgcn_perm(rA2, rA3, PERM_HI); DOT2(acc1, pr, aA1);
    rA0 = rB0; rA1 = rB1; rA2 = rB2; rA3 = rB3; aA0 = aB0; aA1 = aB1;
    rB0 = rC0; rB1 = rC1; rB2 = rC2; rB3 = rC3; aB0 = aC0; aB1 = aC1;
    rC0 = n0;  rC1 = n1;  rC2 = n2;  rC3 = n3;  aC0 = aN0; aC1 = aN1;
  }
  float inv = 1.f / den2[n];
  unsigned xv = ((const unsigned*)(xb + (size_t)n * DD))[slab * 64 + lane];
  float2 o2;
  o2.x = elu(acc0 * inv) + bf2f((u16)(xv & 0xFFFFu));
  o2.y = elu(acc1 * inv) + bf2f((u16)(xv >> 16));
  *(float2*)(out + (size_t)n * DD + slab * 128 + lane * 2) = o2;
}

// ---------------- launcher ----------------
extern "C" void kernel_launch(void* const* d_in, const int* in_sizes, int n_in,
                              void* d_out, int out_size, void* d_ws, size_t ws_size,
                              hipStream_t stream){
  const float* h   = (const float*)d_in[0];
  const float* W1  = (const float*)d_in[1];
  const float* a1  = (const float*)d_in[2];
  const float* Wout= (const float*)d_in[3];
  const float* aout= (const float*)d_in[4];
  const int* src   = (const int*)d_in[5];
  const int* dst   = (const int*)d_in[6];
  float* out = (float*)d_out;
  const int N = in_sizes[0] / DD;     // 16384
  const int E = in_sizes[5];          // 540672
  const int EP = E + 3 * N + 512;     // padded-CSR capacity (<=3 pads/node + prefetch slack)
  const int ep2 = EP >> 1;            // pair capacity

  char* p = (char*)d_ws;
  auto alloc = [&](size_t bytes) -> char* {
    char* r = p;
    p += (bytes + 255) & ~(size_t)255;
    return r;
  };
  u16* xb    = (u16*)alloc((size_t)N * DD * 2);
  u16* z1b   = (u16*)alloc((size_t)(N + 1) * DD * 2);   // +1: zero sentinel row; reused as z2b
  u16* hcat  = (u16*)alloc((size_t)N * DD * 2);
  u16* wbt1  = (u16*)alloc((size_t)DD * DD * 2);
  u16* wbt2  = (u16*)alloc((size_t)DD * DD * 2);
  float* es1 = (float*)alloc(((size_t)N * HH + 8) * 4); // +8: sentinel-read slack
  float* ed1 = (float*)alloc((size_t)N * HH * 4);
  float* es2 = (float*)alloc(((size_t)N + 8) * 4);
  float* ed2 = (float*)alloc((size_t)N * 4);
  float* den1= (float*)alloc((size_t)N * HH * 4);
  float* den2= (float*)alloc((size_t)N * 4);
  int* deg   = (int*)alloc((size_t)N * 4);
  int* ntot  = (int*)alloc((size_t)N * 4);
  int* off   = (int*)alloc((size_t)(N + 1) * 4);
  int* cursor= (int*)alloc((size_t)N * 4);
  int* csr   = (int*)alloc((size_t)EP * 4);
  unsigned* wp1 = (unsigned*)alloc(((size_t)HH * ep2 + 64) * 4);  // [head][pair]
  unsigned* wp2 = (unsigned*)alloc(((size_t)ep2 + 64) * 4);

  // only deg needs zeroing (everything else fully written before read)
  hipMemsetAsync(deg, 0, (size_t)N * 4, stream);

  int n4 = N * DD / 4;
  int prep_threads = n4 + HH * DD * DOO / 8 + DD * DD + E + DD / 4;
  k_prep<<<(prep_threads + 255) / 256, 256, 0, stream>>>(h, xb, W1, wbt1, Wout, wbt2,
                                                         dst, deg, z1b, n4, E, N);
  k_ntot<<<(N + 255) / 256, 256, 0, stream>>>(deg, ntot, N);
  k_scan<<<1, 1024, 0, stream>>>(ntot, off, cursor, N);
  k_scatter<<<(E + 255) / 256, 256, 0, stream>>>(src, dst, off, cursor, csr, E, N);
  k_fillpad<<<(N + 255) / 256, 256, 0, stream>>>(off, cursor, csr, N);

  dim3 gg(DD / 128, N / 128);     // x = n-tile (4), y = m-tile (128): A-panel reuse
  dim3 ga(4 * ((N + 3) / 4));     // (node-group, slab): slab = blockIdx.x & 3 -> XCDs {s, s+4}
  dim3 gw((N + 3) / 4);

  k_gemm<<<gg, 256, 0, stream>>>(xb, wbt1, z1b, N);
  k_scores1<<<(N + 3) / 4, 256, 0, stream>>>(z1b, a1, es1, ed1, N);
  k_edgew1<<<gw, 256, 0, stream>>>(es1, ed1, off, csr, wp1, den1, N, ep2);
  k_agg1<<<ga, 256, 0, stream>>>(z1b, wp1, den1, off, csr, hcat, N, ep2);

  k_gemm<<<gg, 256, 0, stream>>>(hcat, wbt2, z1b, N);
  k_scores2<<<(N + 3) / 4, 256, 0, stream>>>(z1b, aout, es2, ed2, N);
  k_edgew2<<<gw, 256, 0, stream>>>(es2, ed2, off, csr, wp2, den2, N);
  k_agg2<<<ga, 256, 0, stream>>>(z1b, wp2, den2, off, csr, xb, out, N);
}